// Round 8
// baseline (507.857 us; speedup 1.0000x reference)
//
#include <hip/hip_runtime.h>
#include <math.h>

#define H 128
#define NGRAPH 64

using f32x4 = __attribute__((ext_vector_type(4))) float;
using f32x2 = __attribute__((ext_vector_type(2))) float;

__device__ inline float bf2f(ushort u) {
  unsigned int b = ((unsigned int)u) << 16;
  return __builtin_bit_cast(float, b);
}
__device__ inline ushort f2bf(float f) {
  unsigned int u = __builtin_bit_cast(unsigned int, f);
  u = (u + 0x7FFF + ((u >> 16) & 1)) >> 16;  // RNE
  return (ushort)u;
}

// accumulate 8 fp8 channels (uint2) scaled by n into acc[8]
#define ACC8(accv, v, n)                                                                     \
  {                                                                                          \
    f32x2 c;                                                                                 \
    c = __builtin_amdgcn_cvt_pk_f32_fp8((v).x, false);                                       \
    accv[0] = fmaf(n, c[0], accv[0]); accv[1] = fmaf(n, c[1], accv[1]);                      \
    c = __builtin_amdgcn_cvt_pk_f32_fp8((v).x, true);                                        \
    accv[2] = fmaf(n, c[0], accv[2]); accv[3] = fmaf(n, c[1], accv[3]);                      \
    c = __builtin_amdgcn_cvt_pk_f32_fp8((v).y, false);                                       \
    accv[4] = fmaf(n, c[0], accv[4]); accv[5] = fmaf(n, c[1], accv[5]);                      \
    c = __builtin_amdgcn_cvt_pk_f32_fp8((v).y, true);                                        \
    accv[6] = fmaf(n, c[0], accv[6]); accv[7] = fmaf(n, c[1], accv[7]);                      \
  }

// ---------------- merged setup: cvt_x | cvt_w | count (3 block-role ranges) ----------------
// h layout everywhere: two slabs [N][64] fp8; slab s at base + s*N64.
__global__ __launch_bounds__(256) void k_setup(const float* __restrict__ x,
                                               unsigned char* __restrict__ x8,
                                               const float* __restrict__ w,
                                               unsigned char* __restrict__ w8,
                                               const int* __restrict__ col,
                                               int* __restrict__ cnt, int* __restrict__ rank,
                                               int nx4, int nw4, int E, int bx, int bw,
                                               size_t N64) {
  int b = blockIdx.x;
  int t = threadIdx.x;
  if (b < bx) {  // x fp32 -> fp8 split slabs
    int i = b * 256 + t;
    if (i < nx4) {
      float4 v = *(const float4*)(x + (size_t)i * 4);
      int p = __builtin_amdgcn_cvt_pk_fp8_f32(v.x, v.y, 0, false);
      p = __builtin_amdgcn_cvt_pk_fp8_f32(v.z, v.w, p, true);
      int f = i * 4;
      int r = f >> 7, c = f & 127;  // c..c+3 within one 64-block (4|64)
      *(unsigned int*)(x8 + (size_t)(c >> 6) * N64 + (size_t)r * 64 + (c & 63)) = (unsigned int)p;
    }
  } else if (b < bx + bw) {  // weights transpose+cvt: W8[l][j][k] = W[l][k/128][k%128][j]
    int i = (b - bx) * 256 + t;
    if (i < nw4) {
      int f = i * 4;
      int l = f >> 16;
      int j = (f >> 9) & 127;
      int k = f & 511;
      int q = k >> 7, kk = k & 127;
      const float* src = w + (((size_t)(l * 4 + q) * H + kk) * H + j);
      float v0 = src[0], v1 = src[H], v2 = src[2 * H], v3 = src[3 * H];
      int p = __builtin_amdgcn_cvt_pk_fp8_f32(v0, v1, 0, false);
      p = __builtin_amdgcn_cvt_pk_fp8_f32(v2, v3, p, true);
      *(unsigned int*)(w8 + f) = (unsigned int)p;
    }
  } else {  // count: rank[e] = old cnt[col[e]]++ (the ONLY atomic pass)
    int e = (b - bx - bw) * 256 + t;
    if (e < E) rank[e] = atomicAdd(&cnt[col[e]], 1);
  }
}

// ---------------- parallel 3-phase exclusive scan ----------------
__global__ __launch_bounds__(256) void k_scan1(const int* __restrict__ cnt,
                                               int* __restrict__ bsum, int N) {
  int i = blockIdx.x * 256 + threadIdx.x;
  int v = (i < N) ? cnt[i] : 0;
  __shared__ int red[256];
  red[threadIdx.x] = v;
  __syncthreads();
  #pragma unroll
  for (int o = 128; o; o >>= 1) {
    if (threadIdx.x < o) red[threadIdx.x] += red[threadIdx.x + o];
    __syncthreads();
  }
  if (threadIdx.x == 0) bsum[blockIdx.x] = red[0];
}

__global__ __launch_bounds__(256) void k_scan2(const int* __restrict__ bsum,
                                               int* __restrict__ boff, int nb) {
  __shared__ int s[256];
  int t = threadIdx.x;
  int v = (t < nb) ? bsum[t] : 0;
  s[t] = v;
  __syncthreads();
  #pragma unroll
  for (int d = 1; d < 256; d <<= 1) {
    int u = (t >= d) ? s[t - d] : 0;
    __syncthreads();
    s[t] += u;
    __syncthreads();
  }
  if (t < nb) boff[t] = s[t] - v;  // exclusive prefix
}

__global__ __launch_bounds__(256) void k_scan3(const int* __restrict__ cnt,
                                               const int* __restrict__ boff,
                                               int* __restrict__ ptr, int N) {
  int t = threadIdx.x;
  int i = blockIdx.x * 256 + t;
  int v = (i < N) ? cnt[i] : 0;
  __shared__ int s[256];
  s[t] = v;
  __syncthreads();
  #pragma unroll
  for (int d = 1; d < 256; d <<= 1) {
    int u = (t >= d) ? s[t - d] : 0;
    __syncthreads();
    s[t] += u;
    __syncthreads();
  }
  int ex = boff[blockIdx.x] + s[t] - v;
  if (i < N) {
    ptr[i] = ex;
    if (i == N - 1) ptr[N] = ex + v;
  }
}

// ---------------- scatter packed (row:u16 | w:bf16) into CSC order — NO atomics ----------------
__global__ void k_scatter(const int* __restrict__ row, const int* __restrict__ col,
                          const float* __restrict__ w, const int* __restrict__ ptr,
                          const int* __restrict__ rank, unsigned int* __restrict__ es, int E) {
  int e = blockIdx.x * blockDim.x + threadIdx.x;
  if (e < E) {
    int pos = ptr[col[e]] + rank[e];
    es[pos] = ((unsigned int)row[e] & 0xFFFFu) | ((unsigned int)f2bf(w[e]) << 16);
  }
}

// ---------------- per-node degree -> dis = rsqrt(deg) ----------------
__global__ __launch_bounds__(256) void k_degnorm1(const int* __restrict__ ptr,
                                                  const unsigned int* __restrict__ es,
                                                  float* __restrict__ dis, int N) {
  int v = blockIdx.x * blockDim.x + threadIdx.x;
  if (v >= N) return;
  int s = ptr[v], e = ptr[v + 1];
  float d = 0.f;
  for (int i = s; i < e; i++) d += bf2f((ushort)(es[i] >> 16));
  dis[v] = d > 0.f ? rsqrtf(d) : 0.f;
}

// ---------------- per-edge norm: es.hi = bf16(dis[row]*w*dis[col]) ----------------
__global__ __launch_bounds__(256) void k_degnorm2(const int* __restrict__ ptr,
                                                  unsigned int* __restrict__ es,
                                                  const float* __restrict__ dis, int N) {
  int v = blockIdx.x * blockDim.x + threadIdx.x;
  if (v >= N) return;
  int s = ptr[v], e = ptr[v + 1];
  float dv = dis[v];
  for (int i = s; i < e; i++) {
    unsigned int u = es[i];
    float nm = dis[u & 0xFFFFu] * bf2f((ushort)(u >> 16)) * dv;
    es[i] = (u & 0xFFFFu) | ((unsigned int)f2bf(nm) << 16);
  }
}

// ---------------- propagation, channel-split: two independent 64-ch passes ----------------
// Pass = blockIdx range; each pass gathers from a 3.2 MB slab (fits XCD L2).
// 8 lanes per node (8B = 8 fp8 channels per lane), 32 nodes/block, 4-deep pipeline.
__global__ __launch_bounds__(256) void k_prop(const unsigned char* __restrict__ hin8,
                                              unsigned char* __restrict__ hout8,
                                              const int* __restrict__ ptr,
                                              const unsigned int* __restrict__ es,
                                              int N, int nbh, size_t N64) {
  int b = blockIdx.x;
  size_t off = 0;
  if (b >= nbh) { b -= nbh; off = N64; }
  int node = b * 32 + (threadIdx.x >> 3);
  if (node >= N) return;
  int l7 = threadIdx.x & 7;  // channel block: 8 fp8 at byte l7*8
  int s = ptr[node], e = ptr[node + 1];
  float a[8] = {0.f, 0.f, 0.f, 0.f, 0.f, 0.f, 0.f, 0.f};
  float bb[8] = {0.f, 0.f, 0.f, 0.f, 0.f, 0.f, 0.f, 0.f};
  const unsigned char* base = hin8 + off + l7 * 8;
  int i = s;
  for (; i + 3 < e; i += 4) {
    unsigned int u0 = es[i], u1 = es[i + 1], u2 = es[i + 2], u3 = es[i + 3];
    uint2 v0 = *(const uint2*)(base + (size_t)(u0 & 0xFFFFu) * 64);
    uint2 v1 = *(const uint2*)(base + (size_t)(u1 & 0xFFFFu) * 64);
    uint2 v2 = *(const uint2*)(base + (size_t)(u2 & 0xFFFFu) * 64);
    uint2 v3 = *(const uint2*)(base + (size_t)(u3 & 0xFFFFu) * 64);
    float n0 = bf2f((ushort)(u0 >> 16));
    float n1 = bf2f((ushort)(u1 >> 16));
    float n2 = bf2f((ushort)(u2 >> 16));
    float n3 = bf2f((ushort)(u3 >> 16));
    ACC8(a, v0, n0);
    ACC8(bb, v1, n1);
    ACC8(a, v2, n2);
    ACC8(bb, v3, n3);
  }
  for (; i < e; i++) {
    unsigned int u0 = es[i];
    uint2 v0 = *(const uint2*)(base + (size_t)(u0 & 0xFFFFu) * 64);
    float n0 = bf2f((ushort)(u0 >> 16));
    ACC8(a, v0, n0);
  }
  #pragma unroll
  for (int j = 0; j < 8; j++) a[j] += bb[j];
  int p0 = __builtin_amdgcn_cvt_pk_fp8_f32(a[0], a[1], 0, false);
  p0 = __builtin_amdgcn_cvt_pk_fp8_f32(a[2], a[3], p0, true);
  int p1 = __builtin_amdgcn_cvt_pk_fp8_f32(a[4], a[5], 0, false);
  p1 = __builtin_amdgcn_cvt_pk_fp8_f32(a[6], a[7], p1, true);
  *(uint2*)(hout8 + off + (size_t)node * 64 + l7 * 8) =
      make_uint2((unsigned int)p0, (unsigned int)p1);
}

// ---------------- fused TAGConv GEMM (fp8 MFMA): O8 = relu([X0|X1|X2|X3] @ Wcat + b) ----
// X buffers in split-slab layout (row stride 64 within each slab).
__global__ __launch_bounds__(256) void k_fgemm(const unsigned char* __restrict__ X0,
                                               const unsigned char* __restrict__ X1,
                                               const unsigned char* __restrict__ X2,
                                               const unsigned char* __restrict__ X3,
                                               const unsigned char* __restrict__ W8,  // [128][512] fp8 (j-major)
                                               const float* __restrict__ bias,
                                               unsigned char* __restrict__ O8, int N,
                                               size_t N64) {
  __shared__ unsigned char As[128][72];
  __shared__ unsigned char Bs[128][72];
  int t = threadIdx.x;
  int r0 = blockIdx.x * 128;
  int w = t >> 6, lane = t & 63;
  int mw = w >> 1, nw = w & 1;
  int l15 = lane & 15, l4 = lane >> 4;

  f32x4 acc[4][4];
  #pragma unroll
  for (int i = 0; i < 4; i++)
    #pragma unroll
    for (int j = 0; j < 4; j++) acc[i][j] = (f32x4){0.f, 0.f, 0.f, 0.f};

  for (int it = 0; it < 8; ++it) {
    const unsigned char* Xp = (it < 2) ? X0 : (it < 4) ? X1 : (it < 6) ? X2 : X3;
    const unsigned char* Xs = Xp + (size_t)(it & 1) * N64;  // slab for this 64-ch half
    int k0 = it * 64;
    #pragma unroll
    for (int p = 0; p < 2; p++) {
      int idx = t + p * 256;          // 0..511
      int rj = idx >> 2;              // 0..127
      int kc = (idx & 3) << 4;        // 0,16,32,48
      int gr = r0 + rj;
      uint4 av = make_uint4(0, 0, 0, 0);
      if (gr < N) av = *(const uint4*)(Xs + (size_t)gr * 64 + kc);
      *(uint4*)&As[rj][kc] = av;
      *(uint4*)&Bs[rj][kc] = *(const uint4*)(W8 + (size_t)rj * 512 + k0 + kc);
    }
    __syncthreads();
    #pragma unroll
    for (int ks = 0; ks < 2; ks++) {
      int kk = ks * 32 + l4 * 8;
      long a[4], b[4];
      #pragma unroll
      for (int mf = 0; mf < 4; mf++) a[mf] = *(const long*)&As[mw * 64 + mf * 16 + l15][kk];
      #pragma unroll
      for (int nf = 0; nf < 4; nf++) b[nf] = *(const long*)&Bs[nw * 64 + nf * 16 + l15][kk];
      #pragma unroll
      for (int mf = 0; mf < 4; mf++)
        #pragma unroll
        for (int nf = 0; nf < 4; nf++)
          acc[mf][nf] = __builtin_amdgcn_mfma_f32_16x16x32_fp8_fp8(a[mf], b[nf], acc[mf][nf], 0, 0, 0);
    }
    __syncthreads();
  }

  #pragma unroll
  for (int nf = 0; nf < 4; nf++) {
    int colj = nw * 64 + nf * 16 + l15;
    unsigned char* Od = O8 + (size_t)(colj >> 6) * N64 + (colj & 63);
    float bv = bias[colj];
    #pragma unroll
    for (int mf = 0; mf < 4; mf++) {
      int rbase = r0 + mw * 64 + mf * 16 + l4 * 4;
      #pragma unroll
      for (int r = 0; r < 4; r++) {
        int rr = rbase + r;
        if (rr < N) {
          float v = fmaxf(acc[mf][nf][r] + bv, 0.f);
          Od[(size_t)rr * 64] =
              (unsigned char)(__builtin_amdgcn_cvt_pk_fp8_f32(v, v, 0, false) & 0xFF);
        }
      }
    }
  }
}

// ---------------- global mean pool (fp8 split-slab in): parallel atomic sums ----------------
#define POOL_ROWS 64
__global__ __launch_bounds__(256) void k_pool(const unsigned char* __restrict__ h8,
                                              const int* __restrict__ batch,
                                              float* __restrict__ pooled, int N, size_t N64) {
  int r0 = blockIdx.x * POOL_ROWS;
  int j2 = threadIdx.x & 63;   // channel pair: channels 2*j2, 2*j2+1
  int q = threadIdx.x >> 6;    // 0..3: row subset
  int c = 2 * j2;
  const unsigned char* hb = h8 + (size_t)(c >> 6) * N64 + (c & 63);
  int rend = min(r0 + POOL_ROWS, N);
  float a0 = 0.f, a1 = 0.f;
  int cur = -1;
  for (int r = r0 + q; r < rend; r += 4) {
    int g = batch[r];
    if (g != cur) {
      if (cur >= 0) {
        atomicAdd(&pooled[cur * H + c], a0);
        atomicAdd(&pooled[cur * H + c + 1], a1);
      }
      cur = g;
      a0 = a1 = 0.f;
    }
    unsigned int v = *(const ushort*)(hb + (size_t)r * 64);
    f32x2 cc = __builtin_amdgcn_cvt_pk_f32_fp8(v, false);
    a0 += cc[0];
    a1 += cc[1];
  }
  if (cur >= 0) {
    atomicAdd(&pooled[cur * H + c], a0);
    atomicAdd(&pooled[cur * H + c + 1], a1);
  }
}

// ---------------- head: sigmoid((mean @ W1 + b1) @ W2 + b2), bounds inline ----------------
__global__ __launch_bounds__(128) void k_head(const float* __restrict__ pooled,
                                              const int* __restrict__ batch, int N,
                                              const float* __restrict__ w1,
                                              const float* __restrict__ b1,
                                              const float* __restrict__ w2,
                                              const float* __restrict__ b2,
                                              float* __restrict__ out) {
  int g = blockIdx.x;
  int j = threadIdx.x;
  __shared__ float pv[H];
  __shared__ float red[H];
  __shared__ int bnd[2];
  if (j < 2) {
    int target = g + j;
    int lo = 0, hi = N;
    while (lo < hi) {
      int mid = (lo + hi) >> 1;
      if (batch[mid] < target) lo = mid + 1;
      else hi = mid;
    }
    bnd[j] = lo;
  }
  __syncthreads();
  float c = (float)max(bnd[1] - bnd[0], 1);
  pv[j] = pooled[g * H + j] / c;
  __syncthreads();
  float t1 = b1[j];
  #pragma unroll 4
  for (int k = 0; k < H; k++) t1 = fmaf(pv[k], w1[k * H + j], t1);
  red[j] = t1 * w2[j];
  __syncthreads();
  if (j < 64) {
    float s = red[j] + red[j + 64];
    #pragma unroll
    for (int o = 32; o; o >>= 1) s += __shfl_down(s, o);
    if (j == 0) out[g] = 1.f / (1.f + expf(-(s + b2[0])));
  }
}

extern "C" void kernel_launch(void* const* d_in, const int* in_sizes, int n_in,
                              void* d_out, int out_size, void* d_ws, size_t ws_size,
                              hipStream_t stream) {
  const float* x = (const float*)d_in[0];
  const int* eidx = (const int*)d_in[1];
  const float* ew = (const float*)d_in[2];
  const int* batch = (const int*)d_in[3];
  const float* conv_ws = (const float*)d_in[4];  // [5][4][128][128]
  const float* conv_bs = (const float*)d_in[5];  // [5][128]
  const float* lin1_w = (const float*)d_in[6];
  const float* lin1_b = (const float*)d_in[7];
  const float* lin2_w = (const float*)d_in[8];
  const float* lin2_b = (const float*)d_in[9];
  float* out = (float*)d_out;

  const int N = in_sizes[0] / H;  // 50000  (row packing assumes N <= 65535)
  const int E = in_sizes[2];      // 800000
  const int* row = eidx;
  const int* col = eidx + E;
  const size_t N64 = (size_t)N * 64;

  char* p = (char*)d_ws;
  auto alloc = [&](size_t bytes) {
    char* q = p;
    p += (bytes + 255) & ~(size_t)255;
    return q;
  };
  int* cnt = (int*)alloc((size_t)N * 4);
  int* ptrb = (int*)alloc((size_t)(N + 1) * 4);
  int* rank = (int*)alloc((size_t)E * 4);
  float* dis = (float*)alloc((size_t)N * 4);
  unsigned int* es = (unsigned int*)alloc((size_t)E * 4);
  unsigned char* x8 = (unsigned char*)alloc((size_t)N * H);
  unsigned char* C0 = (unsigned char*)alloc((size_t)N * H);
  unsigned char* C1 = (unsigned char*)alloc((size_t)N * H);
  unsigned char* C2 = (unsigned char*)alloc((size_t)N * H);
  unsigned char* C3 = (unsigned char*)alloc((size_t)N * H);
  unsigned char* W8 = (unsigned char*)alloc((size_t)5 * H * 512);
  int* bsum = (int*)alloc(256 * 4);
  int* boff = (int*)alloc(256 * 4);
  float* pooled = (float*)alloc((size_t)NGRAPH * H * 4);

  hipMemsetAsync(cnt, 0, (size_t)N * 4, stream);
  hipMemsetAsync(pooled, 0, (size_t)NGRAPH * H * 4, stream);

  int nx4 = N * H / 4;
  int nw4 = 5 * H * 512 / 4;
  int bx = (nx4 + 255) / 256;
  int bw = (nw4 + 255) / 256;
  int be = (E + 255) / 256;
  int nb = (N + 255) / 256;   // 196 <= 256
  k_setup<<<bx + bw + be, 256, 0, stream>>>(x, x8, conv_ws, W8, col, cnt, rank,
                                            nx4, nw4, E, bx, bw, N64);
  k_scan1<<<nb, 256, 0, stream>>>(cnt, bsum, N);
  k_scan2<<<1, 256, 0, stream>>>(bsum, boff, nb);
  k_scan3<<<nb, 256, 0, stream>>>(cnt, boff, ptrb, N);
  k_scatter<<<be, 256, 0, stream>>>(row, col, ew, ptrb, rank, es, E);
  k_degnorm1<<<nb, 256, 0, stream>>>(ptrb, es, dis, N);
  k_degnorm2<<<nb, 256, 0, stream>>>(ptrb, es, dis, N);

  int gemm_blocks = (N + 127) / 128;
  int nbh = (N + 31) / 32;          // blocks per 64-channel pass
  int prop_blocks = 2 * nbh;        // both passes in one launch

  const unsigned char* P8 = x8;
  for (int layer = 0; layer < 5; layer++) {
    const unsigned char* Wl = W8 + (size_t)layer * H * 512;
    const float* bl = conv_bs + (size_t)layer * H;
    k_prop<<<prop_blocks, 256, 0, stream>>>(P8, C0, ptrb, es, N, nbh, N64);
    k_prop<<<prop_blocks, 256, 0, stream>>>(C0, C1, ptrb, es, N, nbh, N64);
    k_prop<<<prop_blocks, 256, 0, stream>>>(C1, C2, ptrb, es, N, nbh, N64);
    // O8=C3 aliases P8 for layers>=1: each block reads only its own 128 rows of
    // X0 (during staging) and writes those same rows only in the epilogue -> safe.
    k_fgemm<<<gemm_blocks, 256, 0, stream>>>(P8, C0, C1, C2, Wl, bl, C3, N, N64);
    P8 = C3;
  }

  k_pool<<<(N + POOL_ROWS - 1) / POOL_ROWS, 256, 0, stream>>>(P8, batch, pooled, N, N64);
  k_head<<<NGRAPH, 128, 0, stream>>>(pooled, batch, N, lin1_w, lin1_b, lin2_w, lin2_b, out);
}